// Round 1
// baseline (1402.951 us; speedup 1.0000x reference)
//
#include <hip/hip_runtime.h>

#define H_A   2048
#define H_HP  4096
#define V_A   256
#define V_HP  256
#define DEPTH 12

__device__ __forceinline__ float sigmoidf_(float x) { return 1.0f / (1.0f + expf(-x)); }

__device__ __forceinline__ float dot4_(float4 a, float4 b) {
    return a.x * b.x + a.y * b.y + a.z * b.z + a.w * b.w;
}

// Butterfly reduce: every lane ends with the full 64-lane sum (shfl_xor always in-range).
__device__ __forceinline__ float waveReduceSum(float v) {
#pragma unroll
    for (int off = 32; off > 0; off >>= 1) v += __shfl_xor(v, off, 64);
    return v;
}

// ---------------------------------------------------------------------------
// init: h_a = x_a, c_a0 = 0, h_hp = x_hp, c_hp = 0, a_vec = 1/256, logits_hp = 0
// (ws is re-poisoned 0xAA before every timed launch -> must init every call)
// ---------------------------------------------------------------------------
__global__ void k_init(const float* __restrict__ x_a, const float* __restrict__ x_hp,
                       float* __restrict__ h_a, float* __restrict__ c_a0,
                       float* __restrict__ h_hp, float* __restrict__ c_hp,
                       float* __restrict__ a_vec, float* __restrict__ logits_hp)
{
    int i = blockIdx.x * 256 + threadIdx.x;
    if (i < H_A)  { h_a[i] = x_a[i];  c_a0[i] = 0.0f; }
    if (i < H_HP) { h_hp[i] = x_hp[i]; c_hp[i] = 0.0f; }
    if (i < V_A)  { a_vec[i] = 1.0f / 256.0f; logits_hp[i] = 0.0f; }
}

// ---------------------------------------------------------------------------
// k1: fused phase-1 GEMVs (all inputs are previous-step state)
//   waves [0,8192):      gates_a[r]  = W_ih_a[r]·a + W_hh_a[r]·h_a + b_ih_a[r] + b_hh_a[r]
//   waves [8192,10240):  h_sum[r]    = relu(W_sum[r]·h_hp + b_sum[r])
//   waves [10240,26624): gacc_hp[r]  = W_hh_hp[r]·c_hp + b_ih_hp[r] + b_hh_hp[r]
// One wave per row, float4 row reads. skip_c: c_hp == 0 at step 0 (exact skip).
// ---------------------------------------------------------------------------
__global__ __launch_bounds__(256) void k1_fused_gemv(
    const float* __restrict__ W_ih_a, const float* __restrict__ W_hh_a,
    const float* __restrict__ b_ih_a, const float* __restrict__ b_hh_a,
    const float* __restrict__ W_sum,  const float* __restrict__ b_sum,
    const float* __restrict__ W_hh_hp, const float* __restrict__ b_ih_hp,
    const float* __restrict__ b_hh_hp,
    const float* __restrict__ a_vec,  const float* __restrict__ h_a,
    const float* __restrict__ h_hp,   const float* __restrict__ c_hp,
    float* __restrict__ gates_a, float* __restrict__ h_sum_o,
    float* __restrict__ gacc_hp, int skip_c)
{
    const int lane = threadIdx.x & 63;
    const int wave = (blockIdx.x << 2) | (threadIdx.x >> 6);

    if (wave < 8192) {
        const int r = wave;
        const float4* wa = (const float4*)(W_ih_a + (size_t)r * V_A);
        const float4* xa = (const float4*)a_vec;
        float4 w = wa[lane];
        float4 x = xa[lane];
        float acc = dot4_(w, x);
        const float4* wh = (const float4*)(W_hh_a + (size_t)r * H_A);
        const float4* xh = (const float4*)h_a;
#pragma unroll
        for (int it = 0; it < 8; ++it) {
            acc += dot4_(wh[it * 64 + lane], xh[it * 64 + lane]);
        }
        acc = waveReduceSum(acc);
        if (lane == 0) gates_a[r] = acc + b_ih_a[r] + b_hh_a[r];
    } else if (wave < 10240) {
        const int r = wave - 8192;
        const float4* ww = (const float4*)(W_sum + (size_t)r * H_HP);
        const float4* xx = (const float4*)h_hp;
        float acc = 0.0f;
#pragma unroll 4
        for (int it = 0; it < 16; ++it) {
            acc += dot4_(ww[it * 64 + lane], xx[it * 64 + lane]);
        }
        acc = waveReduceSum(acc);
        if (lane == 0) {
            float v = acc + b_sum[r];
            h_sum_o[r] = fmaxf(v, 0.0f);
        }
    } else {
        const int r = wave - 10240;
        float acc = 0.0f;
        if (!skip_c) {
            const float4* ww = (const float4*)(W_hh_hp + (size_t)r * H_HP);
            const float4* xx = (const float4*)c_hp;
#pragma unroll 4
            for (int it = 0; it < 16; ++it) {
                acc += dot4_(ww[it * 64 + lane], xx[it * 64 + lane]);
            }
            acc = waveReduceSum(acc);
        }
        if (lane == 0) gacc_hp[r] = acc + b_ih_hp[r] + b_hh_hp[r];
    }
}

// ---------------------------------------------------------------------------
// k3: arch pointwise LSTM (redundant per block, h into LDS) + W_out_a GEMV.
// c_a double-buffered (c_in read by all blocks, c_out written by block 0 only).
// 64 blocks x 4 waves -> 256 rows of W_out_a.
// ---------------------------------------------------------------------------
__global__ __launch_bounds__(256) void k3_arch(
    const float* __restrict__ gates_a, const float* __restrict__ c_in,
    float* __restrict__ c_out, float* __restrict__ h_a_g,
    const float* __restrict__ W_out_a, const float* __restrict__ b_out_a,
    float* __restrict__ logits_a)
{
    __shared__ float h_s[H_A];
    const int t = threadIdx.x;
#pragma unroll
    for (int k = 0; k < 8; ++k) {
        int e = t + k * 256;
        float gi = gates_a[e];
        float gf = gates_a[H_A + e];
        float gg = gates_a[2 * H_A + e];
        float go = gates_a[3 * H_A + e];
        float c_new = sigmoidf_(gf) * c_in[e] + sigmoidf_(gi) * tanhf(gg);
        float h = sigmoidf_(go) * tanhf(c_new);
        h_s[e] = h;
        if (blockIdx.x == 0) { c_out[e] = c_new; h_a_g[e] = h; }
    }
    __syncthreads();
    const int lane = t & 63;
    const int r = (blockIdx.x << 2) | (t >> 6);
    const float4* w4 = (const float4*)(W_out_a + (size_t)r * H_A);
    const float4* h4 = (const float4*)h_s;
    float acc = 0.0f;
#pragma unroll
    for (int it = 0; it < 8; ++it) {
        acc += dot4_(w4[it * 64 + lane], h4[it * 64 + lane]);
    }
    acc = waveReduceSum(acc);
    if (lane == 0) logits_a[r] = acc + b_out_a[r];
}

// ---------------------------------------------------------------------------
// softmax over 256 elems, one block of 256 threads; writes prob vector twice
// (state vector + output slot).
// ---------------------------------------------------------------------------
__device__ __forceinline__ void softmax256_dev(const float* __restrict__ logits,
                                               float* __restrict__ vec,
                                               float* __restrict__ outp)
{
    __shared__ float sh[4];
    const int t = threadIdx.x;
    const int lane = t & 63, wv = t >> 6;
    float v = logits[t];
    float m = v;
#pragma unroll
    for (int off = 32; off > 0; off >>= 1) m = fmaxf(m, __shfl_xor(m, off, 64));
    if (lane == 0) sh[wv] = m;
    __syncthreads();
    m = fmaxf(fmaxf(sh[0], sh[1]), fmaxf(sh[2], sh[3]));
    __syncthreads();
    float e = expf(v - m);
    float s = waveReduceSum(e);
    if (lane == 0) sh[wv] = s;
    __syncthreads();
    s = sh[0] + sh[1] + sh[2] + sh[3];
    __syncthreads();
    float p = e / s;
    vec[t] = p;
    outp[t] = p;
}

__global__ __launch_bounds__(256) void k4_softmax2(
    const float* __restrict__ logits_a, float* __restrict__ a_vec,
    float* __restrict__ out_a,
    const float* __restrict__ logits_hp, float* __restrict__ ahp_vec,
    float* __restrict__ out_hp)
{
    softmax256_dev(logits_a, a_vec, out_a);
    __syncthreads();
    softmax256_dev(logits_hp, ahp_vec, out_hp);
}

__global__ __launch_bounds__(256) void k_softmax_tail(
    const float* __restrict__ logits_hp, float* __restrict__ ahp_vec,
    float* __restrict__ outp)
{
    softmax256_dev(logits_hp, ahp_vec, outp);
}

// ---------------------------------------------------------------------------
// k5: gacc_hp[r] += W_ih_hp[r] · [a_vec(256), ahp_vec(256)]   (16384 rows x 512)
// ---------------------------------------------------------------------------
__global__ __launch_bounds__(256) void k5_ih_hp(
    const float* __restrict__ W_ih_hp, const float* __restrict__ a_vec,
    const float* __restrict__ ahp_vec, float* __restrict__ gacc_hp)
{
    const int lane = threadIdx.x & 63;
    const int r = (blockIdx.x << 2) | (threadIdx.x >> 6);
    const float4* w4 = (const float4*)(W_ih_hp + (size_t)r * (V_A + V_HP));
    float acc = dot4_(w4[lane], ((const float4*)a_vec)[lane]) +
                dot4_(w4[64 + lane], ((const float4*)ahp_vec)[lane]);
    acc = waveReduceSum(acc);
    if (lane == 0) gacc_hp[r] += acc;
}

// ---------------------------------------------------------------------------
// k6: hp pointwise LSTM with the reference's swapped states:
//   cell-state input is prev_h_hp = [h_a, h_sum];  writes c_hp, h_hp.
// ---------------------------------------------------------------------------
__global__ __launch_bounds__(256) void k6_hp_point(
    const float* __restrict__ gacc_hp, const float* __restrict__ h_a,
    const float* __restrict__ h_sum, float* __restrict__ c_hp,
    float* __restrict__ h_hp)
{
    int e = blockIdx.x * 256 + threadIdx.x;  // 4096
    float gi = gacc_hp[e];
    float gf = gacc_hp[H_HP + e];
    float gg = gacc_hp[2 * H_HP + e];
    float go = gacc_hp[3 * H_HP + e];
    float prev = (e < H_A) ? h_a[e] : h_sum[e - H_A];
    float c = sigmoidf_(gf) * prev + sigmoidf_(gi) * tanhf(gg);
    float h = sigmoidf_(go) * tanhf(c);
    c_hp[e] = c;
    h_hp[e] = h;
}

// ---------------------------------------------------------------------------
// k7: logits_hp = W_out_hp @ h_hp + b_out_hp   (256 rows x 4096)
// ---------------------------------------------------------------------------
__global__ __launch_bounds__(256) void k7_out_hp(
    const float* __restrict__ W_out_hp, const float* __restrict__ b_out_hp,
    const float* __restrict__ h_hp, float* __restrict__ logits_hp)
{
    const int lane = threadIdx.x & 63;
    const int r = (blockIdx.x << 2) | (threadIdx.x >> 6);
    const float4* w4 = (const float4*)(W_out_hp + (size_t)r * H_HP);
    const float4* x4 = (const float4*)h_hp;
    float acc = 0.0f;
#pragma unroll 4
    for (int it = 0; it < 16; ++it) {
        acc += dot4_(w4[it * 64 + lane], x4[it * 64 + lane]);
    }
    acc = waveReduceSum(acc);
    if (lane == 0) logits_hp[r] = acc + b_out_hp[r];
}

// ---------------------------------------------------------------------------

extern "C" void kernel_launch(void* const* d_in, const int* in_sizes, int n_in,
                              void* d_out, int out_size, void* d_ws, size_t ws_size,
                              hipStream_t stream)
{
    const float* x_a      = (const float*)d_in[0];
    const float* x_hp     = (const float*)d_in[1];
    const float* W_ih_a   = (const float*)d_in[2];
    const float* W_hh_a   = (const float*)d_in[3];
    const float* b_ih_a   = (const float*)d_in[4];
    const float* b_hh_a   = (const float*)d_in[5];
    const float* W_out_a  = (const float*)d_in[6];
    const float* b_out_a  = (const float*)d_in[7];
    const float* W_sum    = (const float*)d_in[8];
    const float* b_sum    = (const float*)d_in[9];
    const float* W_ih_hp  = (const float*)d_in[10];
    const float* W_hh_hp  = (const float*)d_in[11];
    const float* b_ih_hp  = (const float*)d_in[12];
    const float* b_hh_hp  = (const float*)d_in[13];
    const float* W_out_hp = (const float*)d_in[14];
    const float* b_out_hp = (const float*)d_in[15];

    float* out = (float*)d_out;
    float* ws  = (float*)d_ws;

    // ws layout (floats); total 42240 floats = 165 KiB
    float* gates_a   = ws;           // 8192
    float* h_sum     = ws + 8192;    // 2048
    float* gacc_hp   = ws + 10240;   // 16384
    float* h_a       = ws + 26624;   // 2048
    float* c_a0      = ws + 28672;   // 2048
    float* c_a1      = ws + 30720;   // 2048
    float* h_hp      = ws + 32768;   // 4096
    float* c_hp      = ws + 36864;   // 4096
    float* logits_a  = ws + 40960;   // 256
    float* logits_hp = ws + 41216;   // 256
    float* a_vec     = ws + 41472;   // 256
    float* ahp_vec   = ws + 41728;   // 256
    float* dummy     = ws + 41984;   // 256 (step-0 a_hp slot, discarded)
    float* c_a[2]    = { c_a0, c_a1 };

    k_init<<<16, 256, 0, stream>>>(x_a, x_hp, h_a, c_a0, h_hp, c_hp, a_vec, logits_hp);

    for (int t = 0; t < DEPTH; ++t) {
        k1_fused_gemv<<<6656, 256, 0, stream>>>(
            W_ih_a, W_hh_a, b_ih_a, b_hh_a, W_sum, b_sum,
            W_hh_hp, b_ih_hp, b_hh_hp,
            a_vec, h_a, h_hp, c_hp,
            gates_a, h_sum, gacc_hp, (t == 0) ? 1 : 0);

        k3_arch<<<64, 256, 0, stream>>>(gates_a, c_a[t & 1], c_a[(t + 1) & 1], h_a,
                                        W_out_a, b_out_a, logits_a);

        k4_softmax2<<<1, 256, 0, stream>>>(
            logits_a, a_vec, out + (size_t)t * V_A,
            logits_hp, ahp_vec,
            (t == 0) ? dummy : out + (size_t)DEPTH * V_A + (size_t)(t - 1) * V_HP);

        k5_ih_hp<<<4096, 256, 0, stream>>>(W_ih_hp, a_vec, ahp_vec, gacc_hp);

        k6_hp_point<<<16, 256, 0, stream>>>(gacc_hp, h_a, h_sum, c_hp, h_hp);

        k7_out_hp<<<64, 256, 0, stream>>>(W_out_hp, b_out_hp, h_hp, logits_hp);
    }

    k_softmax_tail<<<1, 256, 0, stream>>>(
        logits_hp, ahp_vec, out + (size_t)DEPTH * V_A + (size_t)(DEPTH - 1) * V_HP);
}

// Round 2
// 1088.405 us; speedup vs baseline: 1.2890x; 1.2890x over previous
//
#include <hip/hip_runtime.h>
#include <hip/hip_fp16.h>

#define H_A   2048
#define H_HP  4096
#define V_A   256
#define V_HP  256
#define DEPTH 12

struct Half8 { __half2 a, b, c, d; };   // 16 B
struct Half4 { __half2 a, b; };         // 8 B

__device__ __forceinline__ float sigmoidf_(float x) { return 1.0f / (1.0f + expf(-x)); }

__device__ __forceinline__ float dot4_(float4 a, float4 b) {
    return a.x * b.x + a.y * b.y + a.z * b.z + a.w * b.w;
}

__device__ __forceinline__ float dot8h_(Half8 w, float4 x0, float4 x1) {
    float2 wa = __half22float2(w.a), wb = __half22float2(w.b);
    float2 wc = __half22float2(w.c), wd = __half22float2(w.d);
    return wa.x * x0.x + wa.y * x0.y + wb.x * x0.z + wb.y * x0.w +
           wc.x * x1.x + wc.y * x1.y + wd.x * x1.z + wd.y * x1.w;
}

// Butterfly reduce: every lane ends with the full 64-lane sum.
__device__ __forceinline__ float waveReduceSum(float v) {
#pragma unroll
    for (int off = 32; off > 0; off >>= 1) v += __shfl_xor(v, off, 64);
    return v;
}

// ---------------------------------------------------------------------------
// fp32 -> fp16 weight conversion, 8 elems/thread (16B stores)
// ---------------------------------------------------------------------------
__global__ __launch_bounds__(256) void k_f2h(const float* __restrict__ src,
                                             __half* __restrict__ dst, int n8)
{
    int i = blockIdx.x * 256 + threadIdx.x;
    if (i < n8) {
        float4 a = ((const float4*)src)[2 * i];
        float4 b = ((const float4*)src)[2 * i + 1];
        Half8 h;
        h.a = __floats2half2_rn(a.x, a.y);
        h.b = __floats2half2_rn(a.z, a.w);
        h.c = __floats2half2_rn(b.x, b.y);
        h.d = __floats2half2_rn(b.z, b.w);
        ((Half8*)dst)[i] = h;
    }
}

// ---------------------------------------------------------------------------
// init state (ws re-poisoned 0xAA every call -> must init every call)
// ---------------------------------------------------------------------------
__global__ void k_init(const float* __restrict__ x_a, const float* __restrict__ x_hp,
                       float* __restrict__ h_a, float* __restrict__ c_a0,
                       float* __restrict__ h_hp, float* __restrict__ c_hp,
                       float* __restrict__ a_vec, float* __restrict__ logits_hp)
{
    int i = blockIdx.x * 256 + threadIdx.x;
    if (i < H_A)  { h_a[i] = x_a[i];  c_a0[i] = 0.0f; }
    if (i < H_HP) { h_hp[i] = x_hp[i]; c_hp[i] = 0.0f; }
    if (i < V_A)  { a_vec[i] = 1.0f / 256.0f; logits_hp[i] = 0.0f; }
}

// ---------------------------------------------------------------------------
// k1: fused phase-1 GEMVs (fp16 weights, fp32 accumulate)
//   waves [0,8192):      gates_a[r]  = W_ih_a[r]·a + W_hh_a[r]·h_a + biases
//   waves [8192,10240):  h_sum[r]    = relu(W_sum[r]·h_hp + b_sum[r])
//   waves [10240,26624): gacc_hp[r]  = W_hh_hp[r]·c_hp + b_ih_hp[r] + b_hh_hp[r]
// ---------------------------------------------------------------------------
__global__ __launch_bounds__(256) void k1_fused_gemv(
    const __half* __restrict__ hW_ih_a, const __half* __restrict__ hW_hh_a,
    const float* __restrict__ b_ih_a, const float* __restrict__ b_hh_a,
    const __half* __restrict__ hW_sum,  const float* __restrict__ b_sum,
    const __half* __restrict__ hW_hh_hp, const float* __restrict__ b_ih_hp,
    const float* __restrict__ b_hh_hp,
    const float* __restrict__ a_vec,  const float* __restrict__ h_a,
    const float* __restrict__ h_hp,   const float* __restrict__ c_hp,
    float* __restrict__ gates_a, float* __restrict__ h_sum_o,
    float* __restrict__ gacc_hp, int skip_c)
{
    const int lane = threadIdx.x & 63;
    const int wave = (blockIdx.x << 2) | (threadIdx.x >> 6);

    if (wave < 8192) {
        const int r = wave;
        // ih: 256 cols -> 4 halves/lane
        Half4 w = ((const Half4*)(hW_ih_a + (size_t)r * V_A))[lane];
        float4 x = ((const float4*)a_vec)[lane];
        float2 w0 = __half22float2(w.a), w1 = __half22float2(w.b);
        float acc = w0.x * x.x + w0.y * x.y + w1.x * x.z + w1.y * x.w;
        // hh: 2048 cols -> 4 iters of 8 halves/lane
        const Half8* wh = (const Half8*)(hW_hh_a + (size_t)r * H_A);
        const float4* xh = (const float4*)h_a;
#pragma unroll
        for (int it = 0; it < 4; ++it) {
            int idx = it * 64 + lane;
            acc += dot8h_(wh[idx], xh[2 * idx], xh[2 * idx + 1]);
        }
        acc = waveReduceSum(acc);
        if (lane == 0) gates_a[r] = acc + b_ih_a[r] + b_hh_a[r];
    } else if (wave < 10240) {
        const int r = wave - 8192;
        const Half8* ww = (const Half8*)(hW_sum + (size_t)r * H_HP);
        const float4* xx = (const float4*)h_hp;
        float acc = 0.0f;
#pragma unroll
        for (int it = 0; it < 8; ++it) {
            int idx = it * 64 + lane;
            acc += dot8h_(ww[idx], xx[2 * idx], xx[2 * idx + 1]);
        }
        acc = waveReduceSum(acc);
        if (lane == 0) h_sum_o[r] = fmaxf(acc + b_sum[r], 0.0f);
    } else {
        const int r = wave - 10240;
        float acc = 0.0f;
        if (!skip_c) {
            const Half8* ww = (const Half8*)(hW_hh_hp + (size_t)r * H_HP);
            const float4* xx = (const float4*)c_hp;
#pragma unroll
            for (int it = 0; it < 8; ++it) {
                int idx = it * 64 + lane;
                acc += dot8h_(ww[idx], xx[2 * idx], xx[2 * idx + 1]);
            }
            acc = waveReduceSum(acc);
        }
        if (lane == 0) gacc_hp[r] = acc + b_ih_hp[r] + b_hh_hp[r];
    }
}

// ---------------------------------------------------------------------------
// k3: arch pointwise LSTM (redundant per block, h into LDS) + W_out_a GEMV
// (fp32 weights kept for the small output matrix — precision hedge).
// ---------------------------------------------------------------------------
__global__ __launch_bounds__(256) void k3_arch(
    const float* __restrict__ gates_a, const float* __restrict__ c_in,
    float* __restrict__ c_out, float* __restrict__ h_a_g,
    const float* __restrict__ W_out_a, const float* __restrict__ b_out_a,
    float* __restrict__ logits_a)
{
    __shared__ float h_s[H_A];
    const int t = threadIdx.x;
#pragma unroll
    for (int k = 0; k < 8; ++k) {
        int e = t + k * 256;
        float gi = gates_a[e];
        float gf = gates_a[H_A + e];
        float gg = gates_a[2 * H_A + e];
        float go = gates_a[3 * H_A + e];
        float c_new = sigmoidf_(gf) * c_in[e] + sigmoidf_(gi) * tanhf(gg);
        float h = sigmoidf_(go) * tanhf(c_new);
        h_s[e] = h;
        if (blockIdx.x == 0) { c_out[e] = c_new; h_a_g[e] = h; }
    }
    __syncthreads();
    const int lane = t & 63;
    const int r = (blockIdx.x << 2) | (t >> 6);
    const float4* w4 = (const float4*)(W_out_a + (size_t)r * H_A);
    const float4* h4 = (const float4*)h_s;
    float acc = 0.0f;
#pragma unroll
    for (int it = 0; it < 8; ++it) {
        acc += dot4_(w4[it * 64 + lane], h4[it * 64 + lane]);
    }
    acc = waveReduceSum(acc);
    if (lane == 0) logits_a[r] = acc + b_out_a[r];
}

// ---------------------------------------------------------------------------
// softmax over 256 elems, one block of 256 threads
// ---------------------------------------------------------------------------
__device__ __forceinline__ void softmax256_dev(const float* __restrict__ logits,
                                               float* __restrict__ vec,
                                               float* __restrict__ outp)
{
    __shared__ float sh[4];
    const int t = threadIdx.x;
    const int lane = t & 63, wv = t >> 6;
    float v = logits[t];
    float m = v;
#pragma unroll
    for (int off = 32; off > 0; off >>= 1) m = fmaxf(m, __shfl_xor(m, off, 64));
    if (lane == 0) sh[wv] = m;
    __syncthreads();
    m = fmaxf(fmaxf(sh[0], sh[1]), fmaxf(sh[2], sh[3]));
    __syncthreads();
    float e = expf(v - m);
    float s = waveReduceSum(e);
    if (lane == 0) sh[wv] = s;
    __syncthreads();
    s = sh[0] + sh[1] + sh[2] + sh[3];
    __syncthreads();
    float p = e / s;
    vec[t] = p;
    outp[t] = p;
}

__global__ __launch_bounds__(256) void k4_softmax2(
    const float* __restrict__ logits_a, float* __restrict__ a_vec,
    float* __restrict__ out_a,
    const float* __restrict__ logits_hp, float* __restrict__ ahp_vec,
    float* __restrict__ out_hp)
{
    softmax256_dev(logits_a, a_vec, out_a);
    __syncthreads();
    softmax256_dev(logits_hp, ahp_vec, out_hp);
}

__global__ __launch_bounds__(256) void k_softmax_tail(
    const float* __restrict__ logits_hp, float* __restrict__ ahp_vec,
    float* __restrict__ outp)
{
    softmax256_dev(logits_hp, ahp_vec, outp);
}

// ---------------------------------------------------------------------------
// k5: gacc_hp[r] += W_ih_hp[r] · [a_vec(256), ahp_vec(256)]  (fp16 weights)
// 512 cols -> exactly 8 halves/lane.
// ---------------------------------------------------------------------------
__global__ __launch_bounds__(256) void k5_ih_hp(
    const __half* __restrict__ hW_ih_hp, const float* __restrict__ a_vec,
    const float* __restrict__ ahp_vec, float* __restrict__ gacc_hp)
{
    const int lane = threadIdx.x & 63;
    const int r = (blockIdx.x << 2) | (threadIdx.x >> 6);
    Half8 w = ((const Half8*)(hW_ih_hp + (size_t)r * (V_A + V_HP)))[lane];
    const float* xv = (lane < 32) ? (a_vec + 8 * lane) : (ahp_vec + 8 * lane - 256);
    float4 x0 = ((const float4*)xv)[0];
    float4 x1 = ((const float4*)xv)[1];
    float acc = dot8h_(w, x0, x1);
    acc = waveReduceSum(acc);
    if (lane == 0) gacc_hp[r] += acc;
}

// ---------------------------------------------------------------------------
// k6: hp pointwise LSTM (reference's swapped states: cell input = [h_a, h_sum])
// ---------------------------------------------------------------------------
__global__ __launch_bounds__(256) void k6_hp_point(
    const float* __restrict__ gacc_hp, const float* __restrict__ h_a,
    const float* __restrict__ h_sum, float* __restrict__ c_hp,
    float* __restrict__ h_hp)
{
    int e = blockIdx.x * 256 + threadIdx.x;  // 4096
    float gi = gacc_hp[e];
    float gf = gacc_hp[H_HP + e];
    float gg = gacc_hp[2 * H_HP + e];
    float go = gacc_hp[3 * H_HP + e];
    float prev = (e < H_A) ? h_a[e] : h_sum[e - H_A];
    float c = sigmoidf_(gf) * prev + sigmoidf_(gi) * tanhf(gg);
    float h = sigmoidf_(go) * tanhf(c);
    c_hp[e] = c;
    h_hp[e] = h;
}

// ---------------------------------------------------------------------------
// k7: logits_hp = W_out_hp @ h_hp + b_out_hp  (fp32 weights, small)
// ---------------------------------------------------------------------------
__global__ __launch_bounds__(256) void k7_out_hp(
    const float* __restrict__ W_out_hp, const float* __restrict__ b_out_hp,
    const float* __restrict__ h_hp, float* __restrict__ logits_hp)
{
    const int lane = threadIdx.x & 63;
    const int r = (blockIdx.x << 2) | (threadIdx.x >> 6);
    const float4* w4 = (const float4*)(W_out_hp + (size_t)r * H_HP);
    const float4* x4 = (const float4*)h_hp;
    float acc = 0.0f;
#pragma unroll 4
    for (int it = 0; it < 16; ++it) {
        acc += dot4_(w4[it * 64 + lane], x4[it * 64 + lane]);
    }
    acc = waveReduceSum(acc);
    if (lane == 0) logits_hp[r] = acc + b_out_hp[r];
}

// ---------------------------------------------------------------------------

extern "C" void kernel_launch(void* const* d_in, const int* in_sizes, int n_in,
                              void* d_out, int out_size, void* d_ws, size_t ws_size,
                              hipStream_t stream)
{
    const float* x_a      = (const float*)d_in[0];
    const float* x_hp     = (const float*)d_in[1];
    const float* W_ih_a   = (const float*)d_in[2];
    const float* W_hh_a   = (const float*)d_in[3];
    const float* b_ih_a   = (const float*)d_in[4];
    const float* b_hh_a   = (const float*)d_in[5];
    const float* W_out_a  = (const float*)d_in[6];
    const float* b_out_a  = (const float*)d_in[7];
    const float* W_sum    = (const float*)d_in[8];
    const float* b_sum    = (const float*)d_in[9];
    const float* W_ih_hp  = (const float*)d_in[10];
    const float* W_hh_hp  = (const float*)d_in[11];
    const float* b_ih_hp  = (const float*)d_in[12];
    const float* b_hh_hp  = (const float*)d_in[13];
    const float* W_out_hp = (const float*)d_in[14];
    const float* b_out_hp = (const float*)d_in[15];

    float* out = (float*)d_out;

    // --- ws layout ---
    // fp16 weights first (16B-aligned since d_ws is), then fp32 state.
    __half* hW_ih_a  = (__half*)d_ws;                       //  2,097,152 halves
    __half* hW_hh_a  = hW_ih_a + 2097152;                   // 16,777,216
    __half* hW_sum   = hW_hh_a + 16777216;                  //  8,388,608
    __half* hW_ih_hp = hW_sum + 8388608;                    //  8,388,608
    __half* hW_hh_hp = hW_ih_hp + 8388608;                  // 67,108,864
    float* ws = (float*)(hW_hh_hp + 67108864);              // fp32 state region

    float* gates_a   = ws;           // 8192
    float* h_sum     = ws + 8192;    // 2048
    float* gacc_hp   = ws + 10240;   // 16384
    float* h_a       = ws + 26624;   // 2048
    float* c_a0      = ws + 28672;   // 2048
    float* c_a1      = ws + 30720;   // 2048
    float* h_hp      = ws + 32768;   // 4096
    float* c_hp      = ws + 36864;   // 4096
    float* logits_a  = ws + 40960;   // 256
    float* logits_hp = ws + 41216;   // 256
    float* a_vec     = ws + 41472;   // 256
    float* ahp_vec   = ws + 41728;   // 256
    float* dummy     = ws + 41984;   // 256 (step-0 a_hp slot, discarded)
    float* c_a[2]    = { c_a0, c_a1 };

    // one-time (per call) fp32 -> fp16 weight conversion
    k_f2h<<<(2097152 / 8 + 255) / 256, 256, 0, stream>>>(W_ih_a, hW_ih_a, 2097152 / 8);
    k_f2h<<<(16777216 / 8 + 255) / 256, 256, 0, stream>>>(W_hh_a, hW_hh_a, 16777216 / 8);
    k_f2h<<<(8388608 / 8 + 255) / 256, 256, 0, stream>>>(W_sum, hW_sum, 8388608 / 8);
    k_f2h<<<(8388608 / 8 + 255) / 256, 256, 0, stream>>>(W_ih_hp, hW_ih_hp, 8388608 / 8);
    k_f2h<<<(67108864 / 8 + 255) / 256, 256, 0, stream>>>(W_hh_hp, hW_hh_hp, 67108864 / 8);

    k_init<<<16, 256, 0, stream>>>(x_a, x_hp, h_a, c_a0, h_hp, c_hp, a_vec, logits_hp);

    for (int t = 0; t < DEPTH; ++t) {
        k1_fused_gemv<<<6656, 256, 0, stream>>>(
            hW_ih_a, hW_hh_a, b_ih_a, b_hh_a, hW_sum, b_sum,
            hW_hh_hp, b_ih_hp, b_hh_hp,
            a_vec, h_a, h_hp, c_hp,
            gates_a, h_sum, gacc_hp, (t == 0) ? 1 : 0);

        k3_arch<<<64, 256, 0, stream>>>(gates_a, c_a[t & 1], c_a[(t + 1) & 1], h_a,
                                        W_out_a, b_out_a, logits_a);

        k4_softmax2<<<1, 256, 0, stream>>>(
            logits_a, a_vec, out + (size_t)t * V_A,
            logits_hp, ahp_vec,
            (t == 0) ? dummy : out + (size_t)DEPTH * V_A + (size_t)(t - 1) * V_HP);

        k5_ih_hp<<<4096, 256, 0, stream>>>(hW_ih_hp, a_vec, ahp_vec, gacc_hp);

        k6_hp_point<<<16, 256, 0, stream>>>(gacc_hp, h_a, h_sum, c_hp, h_hp);

        k7_out_hp<<<64, 256, 0, stream>>>(W_out_hp, b_out_hp, h_hp, logits_hp);
    }

    k_softmax_tail<<<1, 256, 0, stream>>>(
        logits_hp, ahp_vec, out + (size_t)DEPTH * V_A + (size_t)(DEPTH - 1) * V_HP);
}